// Round 7
// baseline (665.765 us; speedup 1.0000x reference)
//
#include <hip/hip_runtime.h>
#include <stdint.h>
#include <math.h>

// ---------------------------------------------------------------------------
// HippocampalFastWeight on MI355X (gfx950)
// B=8, T=2048, D=512, N=2048, K_CA3=64
// Round 14: batch->XCD pinning for gram+succ. r13 counters: gram FETCH 337MB
// vs 32MB unique, WRITE 348MB, MfmaUtil 7% -> L2-miss-traffic-bound. Cause:
// dim3(136,1,8) gives id%8 = tile%8, so every XCD interleaves all 8 batches
// (32MB working set vs 4MB L2 -> thrash). Fix: 1D grid, batch = id % 8 ->
// by the id%8->XCD round-robin rule, each XCD runs ONE batch whose full
// 4MB input is L2-resident; staging reads become L2 hits. Same decode for
// succ (consecutive rem on one XCD -> A-panel reused 16x, STs L2-resident).
// GEMM cores, epilogues, and all other kernels unchanged from r13.
// ---------------------------------------------------------------------------

typedef __attribute__((ext_vector_type(8))) short bf16x8;
typedef __attribute__((ext_vector_type(8))) unsigned short u16x8;
typedef __attribute__((ext_vector_type(8))) unsigned char u8x8;
typedef __attribute__((ext_vector_type(4))) float f32x4;
typedef __attribute__((ext_vector_type(4))) int i32x4;
typedef __attribute__((ext_vector_type(8))) int i32x8;

#define GLD_LDS16(gp, lp)                                     \
  __builtin_amdgcn_global_load_lds(                           \
      (const __attribute__((address_space(1))) void*)(gp),    \
      (__attribute__((address_space(3))) void*)(lp), 16, 0, 0)

__device__ __forceinline__ uint16_t f2bf(float f) {
  uint32_t u = __float_as_uint(f);
  uint32_t r = u + 0x7FFFu + ((u >> 16) & 1u);
  return (uint16_t)(r >> 16);
}
__device__ __forceinline__ float bf2f(unsigned u) {
  return __uint_as_float(u << 16);
}

// f32 -> fp8 e4m3fn (inputs non-negative, < 448 here)
__device__ __forceinline__ uint8_t f2fp8(float f) {
#if __has_builtin(__builtin_amdgcn_cvt_pk_fp8_f32)
  return (uint8_t)(__builtin_amdgcn_cvt_pk_fp8_f32(f, 0.f, 0, false) & 0xFF);
#else
  if (!(f > 0.f)) return 0;
  if (f >= 448.f) return 0x7E;
  uint32_t u = __float_as_uint(f);
  int e = (int)((u >> 23) & 255) - 127;
  uint32_t m = u & 0x7FFFFFu;
  if (e < -6) {
    float q = f * 512.f;
    int qi = (int)(q + 0.5f);
    if (qi > 7) return 0x08;
    return (uint8_t)qi;
  }
  uint32_t keep = m >> 20;
  uint32_t rem = m & 0xFFFFFu;
  if (rem > 0x80000u || (rem == 0x80000u && (keep & 1))) keep++;
  uint32_t ee = (uint32_t)(e + 7);
  if (keep == 8) { keep = 0; ee++; }
  if (ee >= 16) return 0x7E;
  return (uint8_t)((ee << 3) | keep);
#endif
}

// bits of 64-bit mask strictly below this lane
__device__ __forceinline__ int bits_below(unsigned long long m) {
  return __builtin_amdgcn_mbcnt_hi((unsigned)(m >> 32),
                                   __builtin_amdgcn_mbcnt_lo((unsigned)m, 0));
}

// ------------------------------- cast --------------------------------------
__global__ __launch_bounds__(256) void cast_f32_bf16_k(
    const float* __restrict__ s, uint16_t* __restrict__ d, long long n) {
  long long i = (long long)blockIdx.x * 256 + threadIdx.x;
  long long stride = (long long)gridDim.x * 256;
  for (; i < n; i += stride) d[i] = f2bf(s[i]);
}

__global__ __launch_bounds__(256) void zero_f32_k(float* __restrict__ p, long long n) {
  long long i = (long long)blockIdx.x * 256 + threadIdx.x;
  if (i < n) p[i] = 0.f;
}

// ------------- transpose up_W (D x N fp32 -> N x D bf16) -------------------
__global__ __launch_bounds__(256) void transpose_upw_k(
    const float* __restrict__ src, uint16_t* __restrict__ dst, int D, int N) {
  __shared__ float t[32][33];
  int n0 = blockIdx.x * 32, d0 = blockIdx.y * 32;
  int lx = threadIdx.x & 31, ly = threadIdx.x >> 5;
#pragma unroll
  for (int r = 0; r < 4; ++r) {
    int d = d0 + ly + r * 8;
    t[ly + r * 8][lx] = src[(long long)d * N + n0 + lx];
  }
  __syncthreads();
#pragma unroll
  for (int r = 0; r < 4; ++r) {
    int n = n0 + ly + r * 8;
    dst[(long long)n * D + d0 + lx] = f2bf(t[lx][ly + r * 8]);
  }
}

// --------------------------- bf16 GEMM -------------------------------------
#define EPI_RELU_BF16 0
#define EPI_SIG 2

template <int EPI>
__global__ __launch_bounds__(256) void gemm_bt_k(
    const uint16_t* __restrict__ A, const uint16_t* __restrict__ B,
    void* __restrict__ Cv, const float* __restrict__ bias,
    int M, int N, int K) {
  __shared__ __align__(16) uint16_t As[128 * 32];
  __shared__ __align__(16) uint16_t Bs[128 * 32];
  const int tid = threadIdx.x;
  const int lane = tid & 63;
  const int wave = tid >> 6;
  const int m0 = blockIdx.x * 128;
  const int n0 = blockIdx.y * 128;
  const int wm = (wave & 1) * 64;
  const int wn = (wave >> 1) * 64;
  const int quad = lane >> 4;
  const int l16 = lane & 15;

  f32x4 acc[4][4];
#pragma unroll
  for (int i = 0; i < 4; ++i)
#pragma unroll
    for (int j = 0; j < 4; ++j) acc[i][j] = (f32x4){0.f, 0.f, 0.f, 0.f};

  const int srow = wave * 16 + (lane >> 2);
  const int sseg = lane & 3;
  const long long arow0 = (long long)(m0 + srow) * K + sseg * 8;
  const long long brow0 = (long long)(n0 + srow) * K + sseg * 8;

  for (int k0 = 0; k0 < K; k0 += 32) {
#pragma unroll
    for (int r = 0; r < 2; ++r) {
      GLD_LDS16(A + arow0 + (long long)r * 64 * K + k0,
                &As[(r * 64 + wave * 16) * 32]);
      GLD_LDS16(B + brow0 + (long long)r * 64 * K + k0,
                &Bs[(r * 64 + wave * 16) * 32]);
    }
    __syncthreads();
    bf16x8 af[4], bfr[4];
#pragma unroll
    for (int i = 0; i < 4; ++i)
      af[i] = *(const bf16x8*)(&As[(wm + i * 16 + l16) * 32 + quad * 8]);
#pragma unroll
    for (int j = 0; j < 4; ++j)
      bfr[j] = *(const bf16x8*)(&Bs[(wn + j * 16 + l16) * 32 + quad * 8]);
#pragma unroll
    for (int i = 0; i < 4; ++i)
#pragma unroll
      for (int j = 0; j < 4; ++j)
        acc[i][j] = __builtin_amdgcn_mfma_f32_16x16x32_bf16(af[i], bfr[j], acc[i][j], 0, 0, 0);
    __syncthreads();
  }

#pragma unroll
  for (int i = 0; i < 4; ++i) {
#pragma unroll
    for (int j = 0; j < 4; ++j) {
#pragma unroll
      for (int r = 0; r < 4; ++r) {
        int row = m0 + wm + i * 16 + quad * 4 + r;
        int col = n0 + wn + j * 16 + l16;
        float v = acc[i][j][r];
        if (EPI == EPI_RELU_BF16) {
          uint16_t* C = (uint16_t*)Cv;
          C[(long long)row * N + col] = f2bf(v > 0.f ? v : 0.f);
        } else {
          float* C = (float*)Cv;
          float z = v + bias[col];
          C[(long long)row * N + col] = 1.f / (1.f + __expf(-z));
        }
      }
    }
  }
}

// ---------------- shared MX-fp8 128x128 pipelined GEMM core ----------------
// mfma_scale_f32_16x16x128_f8f6f4, fmt fp8/fp8, unit scales (e8m0 127 = 1.0).
// 8 waves 4Mx2N, per-wave 32x64 (acc 8 frags = 32 VGPR). BK=128, 16 iters.
// LDS: LA/LB [2][128][128] = 32KB each, 64KB total -> 2 blocks/CU.
// Swizzle (128B rows, 16B slots): LDS(r,s) = global(r, s ^ ((r>>1)&7)).
// A/B frag (K=128): lane holds row=l16, k=(lane>>4)*32..+31 -> 2 b128 reads
// at slots (2q)^X, (2q+1)^X, X = l16>>1. Exactly 8 lanes/slot = b128 floor.
// Pipeline: 2-deep prefetch; per iter: RD frags; lgkm0+barrier; stage tile
// t+2 into just-read buffer; 8 MFMA; vmcnt(4) [counted]; barrier.
__device__ __forceinline__ i32x8 rd32(const uint8_t* base, int o0, int o1) {
  i32x4 lo = *(const i32x4*)(base + o0);
  i32x4 hi = *(const i32x4*)(base + o1);
  i32x8 r;
  r[0] = lo[0]; r[1] = lo[1]; r[2] = lo[2]; r[3] = lo[3];
  r[4] = hi[0]; r[5] = hi[1]; r[6] = hi[2]; r[7] = hi[3];
  return r;
}

#define MXM(a, b, c) \
  __builtin_amdgcn_mfma_scale_f32_16x16x128_f8f6f4(a, b, c, 0, 0, 0, 0x7F, 0, 0x7F)

#define STG_TILE(dstA, dstB, KO)                                               \
  GLD_LDS16(Ag + grow + (KO) + sc0, (dstA) + w * 2048);                        \
  GLD_LDS16(Ag + grow + 16384 + (KO) + (sc0 ^ 64), (dstA) + w * 2048 + 1024);  \
  GLD_LDS16(Bg + grow + (KO) + sc0, (dstB) + w * 2048);                        \
  GLD_LDS16(Bg + grow + 16384 + (KO) + (sc0 ^ 64), (dstB) + w * 2048 + 1024);

#define FP8MX_CORE()                                                           \
  const int lane = threadIdx.x & 63;                                           \
  const int w = threadIdx.x >> 6;                                              \
  const int q = lane >> 4, l16 = lane & 15;                                    \
  const int wm = (w >> 1) * 32, wn = (w & 1) * 64;                             \
  const int sc0 = (((lane & 7) ^ (lane >> 4)) << 4);                           \
  const long long grow = (long long)(w * 16 + (lane >> 3)) * 2048;             \
  f32x4 acc[2][4];                                                             \
  _Pragma("unroll") for (int i = 0; i < 2; ++i)                                \
      _Pragma("unroll") for (int j = 0; j < 4; ++j) acc[i][j] =                \
          (f32x4){0.f, 0.f, 0.f, 0.f};                                         \
  const int s0 = (((2 * q) ^ (l16 >> 1)) << 4);                                \
  const int s1 = (((2 * q + 1) ^ (l16 >> 1)) << 4);                            \
  const int arow0 = (wm + l16) * 128;                                          \
  const int brow0 = (wn + l16) * 128;                                          \
  STG_TILE(&LA[0], &LB[0], 0)                                                  \
  STG_TILE(&LA[16384], &LB[16384], 128)                                        \
  asm volatile("s_waitcnt vmcnt(4)" ::: "memory");                             \
  __builtin_amdgcn_s_barrier();                                                \
  for (int t = 0; t < 16; ++t) {                                               \
    const int c = t & 1;                                                       \
    const uint8_t* la = &LA[c * 16384];                                        \
    const uint8_t* lb = &LB[c * 16384];                                        \
    i32x8 af0 = rd32(la, arow0 + s0, arow0 + s1);                              \
    i32x8 af1 = rd32(la, arow0 + 2048 + s0, arow0 + 2048 + s1);                \
    i32x8 bf0 = rd32(lb, brow0 + s0, brow0 + s1);                              \
    i32x8 bf1 = rd32(lb, brow0 + 2048 + s0, brow0 + 2048 + s1);                \
    i32x8 bf2 = rd32(lb, brow0 + 4096 + s0, brow0 + 4096 + s1);                \
    i32x8 bf3 = rd32(lb, brow0 + 6144 + s0, brow0 + 6144 + s1);                \
    asm volatile("s_waitcnt lgkmcnt(0)" ::: "memory");                         \
    __builtin_amdgcn_sched_barrier(0);                                         \
    __builtin_amdgcn_s_barrier();                                              \
    if (t < 14) {                                                              \
      const long long ko = (long long)(t + 2) * 128;                           \
      uint8_t* sa = &LA[c * 16384];                                            \
      uint8_t* sb = &LB[c * 16384];                                            \
      STG_TILE(sa, sb, ko)                                                     \
    }                                                                          \
    __builtin_amdgcn_s_setprio(1);                                             \
    acc[0][0] = MXM(af0, bf0, acc[0][0]);                                      \
    acc[0][1] = MXM(af0, bf1, acc[0][1]);                                      \
    acc[0][2] = MXM(af0, bf2, acc[0][2]);                                      \
    acc[0][3] = MXM(af0, bf3, acc[0][3]);                                      \
    acc[1][0] = MXM(af1, bf0, acc[1][0]);                                      \
    acc[1][1] = MXM(af1, bf1, acc[1][1]);                                      \
    acc[1][2] = MXM(af1, bf2, acc[1][2]);                                      \
    acc[1][3] = MXM(af1, bf3, acc[1][3]);                                      \
    __builtin_amdgcn_s_setprio(0);                                             \
    if (t < 14) {                                                              \
      asm volatile("s_waitcnt vmcnt(4)" ::: "memory");                         \
    } else if (t == 14) {                                                      \
      asm volatile("s_waitcnt vmcnt(0)" ::: "memory");                         \
    }                                                                          \
    if (t < 15) __builtin_amdgcn_s_barrier();                                  \
  }

// --------------------- fp8 Gram GEMM: G = S·S^T ----------------------------
// 1D grid, batch = id % nb -> with nb=8, all tiles of batch b land on XCD b
// (id%8 round-robin), keeping the 4MB S input L2-resident per XCD.
// Lower-triangle 128x128 tiles: ti 0..15, tj<=ti (136/batch); mirror ti!=tj.
// Epilogue: LDS-staged, full-128B-line bursts.
__global__ __launch_bounds__(512, 4) void gram_mx_k(
    const uint8_t* __restrict__ S, uint8_t* __restrict__ G,
    long long sS, long long sG, int nb) {
  __shared__ __align__(16) uint8_t LA[32768];
  __shared__ __align__(16) uint8_t LB[32768];
  const int b = blockIdx.x % nb;
  int idx = blockIdx.x / nb;
  const uint8_t* Sb = S + (long long)b * sS;
  uint8_t* Gb = G + (long long)b * sG;
  int ti = 0;
  while ((ti + 1) * (ti + 2) / 2 <= idx) ti++;
  const int tj = idx - ti * (ti + 1) / 2;
  const int m0 = ti * 128;
  const int n0 = tj * 128;
  const int T = 2048;
  const uint8_t* Ag = Sb + (long long)m0 * 2048;
  const uint8_t* Bg = Sb + (long long)n0 * 2048;

  FP8MX_CORE()

  // ---- LDS-staged epilogue (both lower halves dead after t=15) ----
  const bool mirror = (ti != tj);
  uint8_t* OD = &LA[0];
  uint8_t* OT = &LB[0];
#pragma unroll
  for (int i = 0; i < 2; ++i) {
#pragma unroll
    for (int j = 0; j < 4; ++j) {
      uint8_t b0 = f2fp8(acc[i][j][0]);
      uint8_t b1 = f2fp8(acc[i][j][1]);
      uint8_t b2 = f2fp8(acc[i][j][2]);
      uint8_t b3 = f2fp8(acc[i][j][3]);
      const int lr = wm + i * 16 + q * 4;
      const int lc = wn + j * 16 + l16;
      OD[(lr + 0) * 128 + lc] = b0;
      OD[(lr + 1) * 128 + lc] = b1;
      OD[(lr + 2) * 128 + lc] = b2;
      OD[(lr + 3) * 128 + lc] = b3;
      if (mirror) {
        uchar4 pk = {b0, b1, b2, b3};
        *(uchar4*)(&OT[lc * 128 + lr]) = pk;
      }
    }
  }
  __syncthreads();
  {
    const int tid = threadIdx.x;
    const int orow = tid >> 2;
    const int ocol = (tid & 3) * 32;
    const i32x4 d0 = *(const i32x4*)(&OD[orow * 128 + ocol]);
    const i32x4 d1 = *(const i32x4*)(&OD[orow * 128 + ocol + 16]);
    *(i32x4*)(&Gb[(long long)(m0 + orow) * T + n0 + ocol]) = d0;
    *(i32x4*)(&Gb[(long long)(m0 + orow) * T + n0 + ocol + 16]) = d1;
    if (mirror) {
      const i32x4 t0 = *(const i32x4*)(&OT[orow * 128 + ocol]);
      const i32x4 t1 = *(const i32x4*)(&OT[orow * 128 + ocol + 16]);
      *(i32x4*)(&Gb[(long long)(n0 + orow) * T + m0 + ocol]) = t0;
      *(i32x4*)(&Gb[(long long)(n0 + orow) * T + m0 + ocol + 16]) = t1;
    }
  }
}

// ------------------- fp8 succ GEMM: succ = relu(G@STs^T - S*wd) ------------
// 1D grid, batch = id % nb (XCD-pinned with nb=8); rem/16 = m-tile (outer),
// rem%16 = n-tile -> on one XCD consecutive blocks sweep n with fixed m:
// G row-panel reused 16x from L2, STs cycles (~L2-sized).
__global__ __launch_bounds__(512, 4) void succ_mx_k(
    const uint8_t* __restrict__ G, const uint8_t* __restrict__ STs,
    uint16_t* __restrict__ C, const float* __restrict__ wd,
    long long sG, long long sB, long long sC, int nb) {
  __shared__ __align__(16) uint8_t LA[32768];
  __shared__ __align__(16) uint8_t LB[32768];
  const int b = blockIdx.x % nb;
  const int rem = blockIdx.x / nb;
  const uint8_t* Ab = G + (long long)b * sG;
  const uint8_t* Bb = STs + (long long)b * sB;
  uint16_t* Cb = C + (long long)b * sC;
  const float* wdb = wd + (long long)b * 2048;
  const int m0 = (rem >> 4) * 128;
  const int n0 = (rem & 15) * 128;
  const int N = 2048;
  const uint8_t* Ag = Ab + (long long)m0 * 2048;
  const uint8_t* Bg = Bb + (long long)n0 * 2048;

  FP8MX_CORE()

  // epilogue: v = acc - S*wd ; S <- relu(v) (bf16, in place)
#pragma unroll
  for (int i = 0; i < 2; ++i) {
#pragma unroll
    for (int j = 0; j < 4; ++j) {
#pragma unroll
      for (int r = 0; r < 4; ++r) {
        int row = m0 + wm + i * 16 + q * 4 + r;
        int col = n0 + wn + j * 16 + l16;
        long long o = (long long)row * N + col;
        float sv = bf2f(Cb[o]);
        float v = acc[i][j][r] - sv * wdb[col];
        Cb[o] = f2bf(v > 0.f ? v : 0.f);
      }
    }
  }
}

// ------- transpose+shift+wdiag: S (TxN bf16) -> STs (NxT fp8), wd ----------
__global__ __launch_bounds__(256) void transpose_shift_wd_k(
    const uint16_t* __restrict__ S, uint8_t* __restrict__ STs,
    float* __restrict__ wd, int T, int N) {
  __shared__ uint16_t tile[65][72];
  __shared__ float wdl[64];
  int t0 = blockIdx.x * 64, n0 = blockIdx.y * 64, b = blockIdx.z;
  const uint16_t* Sb = S + (long long)b * T * N;
  for (int s = threadIdx.x; s < 65 * 8; s += 256) {
    int t = s >> 3, n8 = s & 7;
    u16x8 v = (u16x8){0, 0, 0, 0, 0, 0, 0, 0};
    if (t0 + t < T) v = *(const u16x8*)(Sb + (long long)(t0 + t) * N + n0 + n8 * 8);
    *(u16x8*)(&tile[t][n8 * 8]) = v;
  }
  if (threadIdx.x < 64) wdl[threadIdx.x] = 0.f;
  __syncthreads();
  uint8_t* STsb = STs + (long long)b * N * T;
  for (int s = threadIdx.x; s < 64 * 8; s += 256) {
    int n = s >> 3, t8 = s & 7;
    u8x8 c;
    float part = 0.f;
#pragma unroll
    for (int j = 0; j < 8; ++j) {
      float a = bf2f(tile[t8 * 8 + j][n]);
      float nb = bf2f(tile[t8 * 8 + j + 1][n]);
      c[j] = f2fp8(nb);
      part = fmaf(a, nb, part);
    }
    *(u8x8*)(STsb + (long long)(n0 + n) * T + t0 + t8 * 8) = c;
    atomicAdd(&wdl[n], part);
  }
  __syncthreads();
  if (threadIdx.x < 64)
    atomicAdd(&wd[(long long)b * N + n0 + threadIdx.x], wdl[threadIdx.x]);
}

// ---------------- shared selection core (ballot binary search) -------------
struct SelInfo {
  unsigned th;
  int cg[4];    // count > th per chunk
  int tc[4];    // count == th per chunk
  int r;        // tie slots to take (64 - total greater)
  float inv;    // 1/l2norm of the selected set
};

__device__ __forceinline__ SelInfo select64(const int k_[4][8],
                                            const u16x8 v[4]) {
  unsigned lo = 0, hi = 0x7FFF;
  while (lo < hi) {
    unsigned mid = (lo + hi) >> 1;
    int cnt = 0;
#pragma unroll
    for (int c = 0; c < 4; ++c)
#pragma unroll
      for (int i = 0; i < 8; ++i)
        cnt += (int)__popcll(__ballot(k_[c][i] > (int)mid));
    if (cnt < 64) hi = mid; else lo = mid + 1;
  }
  SelInfo s;
  s.th = lo;
  const int th = (int)lo;
  int cgt = 0;
#pragma unroll
  for (int c = 0; c < 4; ++c) {
    int cg = 0, tc = 0;
#pragma unroll
    for (int i = 0; i < 8; ++i) {
      cg += (int)__popcll(__ballot(k_[c][i] > th));
      tc += (int)__popcll(__ballot(k_[c][i] == th));
    }
    s.cg[c] = cg;
    s.tc[c] = tc;
    cgt += cg;
  }
  s.r = 64 - cgt;
  float ssq = 0.f;
#pragma unroll
  for (int c = 0; c < 4; ++c)
#pragma unroll
    for (int i = 0; i < 8; ++i)
      if (k_[c][i] > th) {
        float f = bf2f((unsigned)v[c][i]);
        ssq = fmaf(f, f, ssq);
      }
#pragma unroll
  for (int off = 32; off >= 1; off >>= 1) ssq += __shfl_xor(ssq, off, 64);
  float thf = bf2f(lo);
  float sumsq = ssq + (float)s.r * thf * thf;
  s.inv = 1.f / fmaxf(sqrtf(sumsq), 1e-10f);
  return s;
}

// ---------- topk1: one wave per row, dense bf16 + fp8 outputs --------------
__global__ __launch_bounds__(256) void topk1_k(
    const uint16_t* __restrict__ H, uint16_t* __restrict__ Sbf,
    uint8_t* __restrict__ Sf8) {
  const int lane = threadIdx.x & 63;
  const int wave = threadIdx.x >> 6;
  const long long row = (long long)blockIdx.x * 4 + wave;
  const uint16_t* h = H + row * 2048;

  u16x8 v[4];
  int k_[4][8];
#pragma unroll
  for (int c = 0; c < 4; ++c) {
    v[c] = *(const u16x8*)(h + c * 512 + lane * 8);
#pragma unroll
    for (int i = 0; i < 8; ++i) k_[c][i] = (int)v[c][i];
  }
  SelInfo s = select64(k_, v);
  const int th = (int)s.th;

  int tiebase = 0;
#pragma unroll
  for (int c = 0; c < 4; ++c) {
    int B = 0;
#pragma unroll
    for (int j = 0; j < 8; ++j)
      B += bits_below(__ballot(k_[c][j] == th));
    u16x8 o16;
    u8x8 o8;
    int own = 0;
#pragma unroll
    for (int i = 0; i < 8; ++i) {
      int kv = k_[c][i];
      bool ist = (kv == th);
      bool sel = (kv > th) || (ist && (tiebase + B + own) < s.r);
      if (ist) own++;
      float nv = sel ? bf2f((unsigned)v[c][i]) * s.inv : 0.f;
      o16[i] = sel ? (unsigned short)f2bf(nv) : (unsigned short)0;
      o8[i] = sel ? f2fp8(nv) : (uint8_t)0;
    }
    *(u16x8*)(Sbf + row * 2048 + c * 512 + lane * 8) = o16;
    *(u8x8*)(Sf8 + row * 2048 + c * 512 + lane * 8) = o8;
    tiebase += s.tc[c];
  }
}

// -------- topk2 + final: one wave per row, per-wave LDS slots, gather ------
__global__ __launch_bounds__(256) void topk2_final_k(
    const uint16_t* __restrict__ H, const float* __restrict__ x,
    const float* __restrict__ g, const uint16_t* __restrict__ upTb,
    float* __restrict__ out) {
  const int lane = threadIdx.x & 63;
  const int wave = threadIdx.x >> 6;
  const long long row = (long long)blockIdx.x * 4 + wave;
  const uint16_t* h = H + row * 2048;

  __shared__ int sidx[4][64];
  __shared__ float sval[4][64];

  u16x8 v[4];
  int k_[4][8];
#pragma unroll
  for (int c = 0; c < 4; ++c) {
    v[c] = *(const u16x8*)(h + c * 512 + lane * 8);
#pragma unroll
    for (int i = 0; i < 8; ++i) k_[c][i] = (int)v[c][i];
  }
  SelInfo s = select64(k_, v);
  const int th = (int)s.th;

  int tiebase = 0;
  int cum = 0;
#pragma unroll
  for (int c = 0; c < 4; ++c) {
    int B = 0;
#pragma unroll
    for (int j = 0; j < 8; ++j)
      B += bits_below(__ballot(k_[c][j] == th));
    int own = 0;
#pragma unroll
    for (int i = 0; i < 8; ++i) {
      int kv = k_[c][i];
      bool ist = (kv == th);
      bool sel = (kv > th) || (ist && (tiebase + B + own) < s.r);
      if (ist) own++;
      unsigned long long sm = __ballot(sel);
      if (sel) {
        int slot = cum + bits_below(sm);
        sidx[wave][slot] = c * 512 + lane * 8 + i;
        sval[wave][slot] = bf2f((unsigned)v[c][i]) * s.inv;
      }
      cum += (int)__popcll(sm);
    }
    tiebase += s.tc[c];
  }
  __syncthreads();

  const int col0 = lane * 8;
  float a[8] = {0.f, 0.f, 0.f, 0.f, 0.f, 0.f, 0.f, 0.f};
#pragma unroll 4
  for (int j = 0; j < 64; ++j) {
    int idx = sidx[wave][j];
    float w = sval[wave][j];
    const u16x8 pk = *(const u16x8*)(upTb + (long long)idx * 512 + col0);
#pragma unroll
    for (int q = 0; q < 8; ++q) a[q] = fmaf(w, bf2f((unsigned)pk[q]), a[q]);
  }
  long long o = row * 512 + col0;
  const float4 xv0 = *(const float4*)(x + o);
  const float4 xv1 = *(const float4*)(x + o + 4);
  const float4 gv0 = *(const float4*)(g + o);
  const float4 gv1 = *(const float4*)(g + o + 4);
  float4 r0, r1;
  r0.x = xv0.x + gv0.x * a[0];
  r0.y = xv0.y + gv0.y * a[1];
  r0.z = xv0.z + gv0.z * a[2];
  r0.w = xv0.w + gv0.w * a[3];
  r1.x = xv1.x + gv1.x * a[4];
  r1.y = xv1.y + gv1.y * a[5];
  r1.z = xv1.z + gv1.z * a[6];
  r1.w = xv1.w + gv1.w * a[7];
  *(float4*)(out + o) = r0;
  *(float4*)(out + o + 4) = r1;
}

// ---------------------------------------------------------------------------
extern "C" void kernel_launch(void* const* d_in, const int* in_sizes, int n_in,
                              void* d_out, int out_size, void* d_ws, size_t ws_size,
                              hipStream_t stream) {
  const float* x = (const float*)d_in[0];
  const float* downW = (const float*)d_in[1];
  const float* upW = (const float*)d_in[2];
  const float* gateW = (const float*)d_in[3];
  const float* gateB = (const float*)d_in[4];
  float* out = (float*)d_out;

  const int B = 8, T = 2048, D = 512, N = 2048;
  const long long BT = (long long)B * T;
  const long long TN = (long long)T * N;
  const long long TD = (long long)T * D;

  char* base = (char*)d_ws;
  size_t off = 0;
  auto take = [&](size_t bytes) {
    size_t o = off;
    off += (bytes + 255) & ~(size_t)255;
    return o;
  };
  size_t o_xb = take((size_t)BT * D * 2);
  size_t o_dwb = take((size_t)N * D * 2);
  size_t o_gwb = take((size_t)D * D * 2);
  size_t o_upT = take((size_t)N * D * 2);
  const size_t fixed = off;
  const size_t perb = (size_t)TN * 2 + (size_t)TN * 2 + (size_t)TN +
                      (size_t)TN + (size_t)N * 4;
  int Bc = 1;
  if (ws_size >= fixed + 8 * perb) Bc = 8;
  else if (ws_size >= fixed + 4 * perb) Bc = 4;
  else if (ws_size >= fixed + 2 * perb) Bc = 2;

  uint16_t* xb = (uint16_t*)(base + o_xb);
  uint16_t* dwb = (uint16_t*)(base + o_dwb);
  uint16_t* gwb = (uint16_t*)(base + o_gwb);
  uint16_t* upTb = (uint16_t*)(base + o_upT);
  char* p = base + fixed;
  uint16_t* R1 = (uint16_t*)p; p += (size_t)TN * 2 * Bc;  // h (bf16) -> G (fp8)
  uint16_t* R2 = (uint16_t*)p; p += (size_t)TN * 2 * Bc;  // S (bf16) -> succ
  uint8_t* R3 = (uint8_t*)p;  p += (size_t)TN * Bc;       // STs fp8 -> g fp32
  uint8_t* R4 = (uint8_t*)p;  p += (size_t)TN * Bc;       // S fp8
  float* wd = (float*)p;

  cast_f32_bf16_k<<<2048, 256, 0, stream>>>(x, xb, BT * D);
  cast_f32_bf16_k<<<512, 256, 0, stream>>>(downW, dwb, (long long)N * D);
  cast_f32_bf16_k<<<128, 256, 0, stream>>>(gateW, gwb, (long long)D * D);
  transpose_upw_k<<<dim3(N / 32, D / 32), 256, 0, stream>>>(upW, upTb, D, N);

  for (int b0 = 0; b0 < B; b0 += Bc) {
    const uint16_t* xc = xb + (long long)b0 * TD;
    gemm_bt_k<EPI_RELU_BF16><<<dim3(Bc * 16, 16, 1), 256, 0, stream>>>(
        xc, dwb, R1, nullptr, Bc * T, N, D);
    topk1_k<<<Bc * T / 4, 256, 0, stream>>>(R1, R2, R4);
    zero_f32_k<<<(Bc * N + 255) / 256, 256, 0, stream>>>(wd, (long long)Bc * N);
    transpose_shift_wd_k<<<dim3(T / 64, N / 64, Bc), 256, 0, stream>>>(
        R2, R3, wd, T, N);
    gram_mx_k<<<dim3(136 * Bc), 512, 0, stream>>>(
        R4, (uint8_t*)R1, TN, (long long)T * T, Bc);
    succ_mx_k<<<dim3(256 * Bc), 512, 0, stream>>>(
        (const uint8_t*)R1, R3, R2, wd, (long long)T * T, TN, TN, Bc);
    gemm_bt_k<EPI_SIG><<<dim3(Bc * 16, D / 128, 1), 256, 0, stream>>>(
        xc, gwb, (float*)R3, gateB, Bc * T, D, D);
    topk2_final_k<<<Bc * T / 4, 256, 0, stream>>>(
        R2, x + (long long)b0 * TD, (const float*)R3, upTb,
        out + (long long)b0 * TD);
  }
}

// Round 8
// 534.805 us; speedup vs baseline: 1.2449x; 1.2449x over previous
//
#include <hip/hip_runtime.h>
#include <stdint.h>
#include <math.h>

// ---------------------------------------------------------------------------
// HippocampalFastWeight on MI355X (gfx950)
// B=8, T=2048, D=512, N=2048, K_CA3=64
// Round 15: revert to the r11-proven fp8 GEMM cores (256x128 tile, BK=64,
// 48KB LDS, (512,4) -> 2 blocks/CU; measured 541us total, succ=114us,
// gram<114us). The r12-14 MX bundle was a measured regression on gram
// (188-216us, WRITE pinned at 348MB) and succ_mx was not demonstrably
// better than succ_fp8_v2's measured 114. Single new variable this round:
// batch->XCD pinning (1D grid, b = id % Bc -> id%8 round-robin puts each
// batch's working set on one XCD's 4MB L2), decode-only, evidenced by
// r14's FETCH 337->242MB on gram_mx. Cores byte-identical to r11.
// ---------------------------------------------------------------------------

typedef __attribute__((ext_vector_type(8))) short bf16x8;
typedef __attribute__((ext_vector_type(8))) unsigned short u16x8;
typedef __attribute__((ext_vector_type(8))) unsigned char u8x8;
typedef __attribute__((ext_vector_type(4))) float f32x4;

#define GLD_LDS16(gp, lp)                                     \
  __builtin_amdgcn_global_load_lds(                           \
      (const __attribute__((address_space(1))) void*)(gp),    \
      (__attribute__((address_space(3))) void*)(lp), 16, 0, 0)

__device__ __forceinline__ uint16_t f2bf(float f) {
  uint32_t u = __float_as_uint(f);
  uint32_t r = u + 0x7FFFu + ((u >> 16) & 1u);
  return (uint16_t)(r >> 16);
}
__device__ __forceinline__ float bf2f(unsigned u) {
  return __uint_as_float(u << 16);
}

// f32 -> fp8 e4m3fn (inputs non-negative, < 448 here)
__device__ __forceinline__ uint8_t f2fp8(float f) {
#if __has_builtin(__builtin_amdgcn_cvt_pk_fp8_f32)
  return (uint8_t)(__builtin_amdgcn_cvt_pk_fp8_f32(f, 0.f, 0, false) & 0xFF);
#else
  if (!(f > 0.f)) return 0;
  if (f >= 448.f) return 0x7E;
  uint32_t u = __float_as_uint(f);
  int e = (int)((u >> 23) & 255) - 127;
  uint32_t m = u & 0x7FFFFFu;
  if (e < -6) {
    float q = f * 512.f;
    int qi = (int)(q + 0.5f);
    if (qi > 7) return 0x08;
    return (uint8_t)qi;
  }
  uint32_t keep = m >> 20;
  uint32_t rem = m & 0xFFFFFu;
  if (rem > 0x80000u || (rem == 0x80000u && (keep & 1))) keep++;
  uint32_t ee = (uint32_t)(e + 7);
  if (keep == 8) { keep = 0; ee++; }
  if (ee >= 16) return 0x7E;
  return (uint8_t)((ee << 3) | keep);
#endif
}

// bits of 64-bit mask strictly below this lane
__device__ __forceinline__ int bits_below(unsigned long long m) {
  return __builtin_amdgcn_mbcnt_hi((unsigned)(m >> 32),
                                   __builtin_amdgcn_mbcnt_lo((unsigned)m, 0));
}

// ------------------------------- cast --------------------------------------
__global__ __launch_bounds__(256) void cast_f32_bf16_k(
    const float* __restrict__ s, uint16_t* __restrict__ d, long long n) {
  long long i = (long long)blockIdx.x * 256 + threadIdx.x;
  long long stride = (long long)gridDim.x * 256;
  for (; i < n; i += stride) d[i] = f2bf(s[i]);
}

__global__ __launch_bounds__(256) void zero_f32_k(float* __restrict__ p, long long n) {
  long long i = (long long)blockIdx.x * 256 + threadIdx.x;
  if (i < n) p[i] = 0.f;
}

// ------------- transpose up_W (D x N fp32 -> N x D bf16) -------------------
__global__ __launch_bounds__(256) void transpose_upw_k(
    const float* __restrict__ src, uint16_t* __restrict__ dst, int D, int N) {
  __shared__ float t[32][33];
  int n0 = blockIdx.x * 32, d0 = blockIdx.y * 32;
  int lx = threadIdx.x & 31, ly = threadIdx.x >> 5;
#pragma unroll
  for (int r = 0; r < 4; ++r) {
    int d = d0 + ly + r * 8;
    t[ly + r * 8][lx] = src[(long long)d * N + n0 + lx];
  }
  __syncthreads();
#pragma unroll
  for (int r = 0; r < 4; ++r) {
    int n = n0 + ly + r * 8;
    dst[(long long)n * D + d0 + lx] = f2bf(t[lx][ly + r * 8]);
  }
}

// --------------------------- bf16 GEMM -------------------------------------
#define EPI_RELU_BF16 0
#define EPI_SIG 2

template <int EPI>
__global__ __launch_bounds__(256) void gemm_bt_k(
    const uint16_t* __restrict__ A, const uint16_t* __restrict__ B,
    void* __restrict__ Cv, const float* __restrict__ bias,
    int M, int N, int K) {
  __shared__ __align__(16) uint16_t As[128 * 32];
  __shared__ __align__(16) uint16_t Bs[128 * 32];
  const int tid = threadIdx.x;
  const int lane = tid & 63;
  const int wave = tid >> 6;
  const int m0 = blockIdx.x * 128;
  const int n0 = blockIdx.y * 128;
  const int wm = (wave & 1) * 64;
  const int wn = (wave >> 1) * 64;
  const int quad = lane >> 4;
  const int l16 = lane & 15;

  f32x4 acc[4][4];
#pragma unroll
  for (int i = 0; i < 4; ++i)
#pragma unroll
    for (int j = 0; j < 4; ++j) acc[i][j] = (f32x4){0.f, 0.f, 0.f, 0.f};

  const int srow = wave * 16 + (lane >> 2);
  const int sseg = lane & 3;
  const long long arow0 = (long long)(m0 + srow) * K + sseg * 8;
  const long long brow0 = (long long)(n0 + srow) * K + sseg * 8;

  for (int k0 = 0; k0 < K; k0 += 32) {
#pragma unroll
    for (int r = 0; r < 2; ++r) {
      GLD_LDS16(A + arow0 + (long long)r * 64 * K + k0,
                &As[(r * 64 + wave * 16) * 32]);
      GLD_LDS16(B + brow0 + (long long)r * 64 * K + k0,
                &Bs[(r * 64 + wave * 16) * 32]);
    }
    __syncthreads();
    bf16x8 af[4], bfr[4];
#pragma unroll
    for (int i = 0; i < 4; ++i)
      af[i] = *(const bf16x8*)(&As[(wm + i * 16 + l16) * 32 + quad * 8]);
#pragma unroll
    for (int j = 0; j < 4; ++j)
      bfr[j] = *(const bf16x8*)(&Bs[(wn + j * 16 + l16) * 32 + quad * 8]);
#pragma unroll
    for (int i = 0; i < 4; ++i)
#pragma unroll
      for (int j = 0; j < 4; ++j)
        acc[i][j] = __builtin_amdgcn_mfma_f32_16x16x32_bf16(af[i], bfr[j], acc[i][j], 0, 0, 0);
    __syncthreads();
  }

#pragma unroll
  for (int i = 0; i < 4; ++i) {
#pragma unroll
    for (int j = 0; j < 4; ++j) {
#pragma unroll
      for (int r = 0; r < 4; ++r) {
        int row = m0 + wm + i * 16 + quad * 4 + r;
        int col = n0 + wn + j * 16 + l16;
        float v = acc[i][j][r];
        if (EPI == EPI_RELU_BF16) {
          uint16_t* C = (uint16_t*)Cv;
          C[(long long)row * N + col] = f2bf(v > 0.f ? v : 0.f);
        } else {
          float* C = (float*)Cv;
          float z = v + bias[col];
          C[(long long)row * N + col] = 1.f / (1.f + __expf(-z));
        }
      }
    }
  }
}

// ----------------- shared fp8 256x128 pipelined GEMM core ------------------
// 8 waves (4M x 2N), per-wave 64x64. BK=64, 32 K-iters, double-buffered LDS:
// LA [2][256][64]=32KB, LB [2][128][64]=16KB -> 48KB -> 2 blocks/CU.
// Staging: 3 full-line GLDs/wave/iter; vmcnt(0)+barrier at iter end.
// Swizzle (64B rows, 16B slots): LDS(r,s) = global(r, s ^ ((r>>1)&3)).
#define RD_AB(KH)                                                              \
  {                                                                            \
    _Pragma("unroll") for (int i = 0; i < 4; ++i) af[i] =                      \
        *(const long*)(la + ((wm + i * 16 + l16) << 6) + koff[KH]);            \
    _Pragma("unroll") for (int j = 0; j < 4; ++j) bfr[j] =                     \
        *(const long*)(lb + ((wn + j * 16 + l16) << 6) + koff[KH]);            \
  }

#define MFMA_4x4()                                                             \
  __builtin_amdgcn_s_setprio(1);                                               \
  _Pragma("unroll") for (int i = 0; i < 4; ++i)                                \
      _Pragma("unroll") for (int j = 0; j < 4; ++j) acc[i][j] =                \
          __builtin_amdgcn_mfma_f32_16x16x32_fp8_fp8(af[i], bfr[j],            \
                                                     acc[i][j], 0, 0, 0);      \
  __builtin_amdgcn_s_setprio(0);

#define STG_ALL()                                                              \
  GLD_LDS16(Ag + (long long)(w * 32 + (lane >> 2)) * 2048 + ko + sc,           \
            sa + w * 2048);                                                    \
  GLD_LDS16(Ag + (long long)(w * 32 + 16 + (lane >> 2)) * 2048 + ko + sc,      \
            sa + w * 2048 + 1024);                                             \
  GLD_LDS16(Bg + (long long)(w * 16 + (lane >> 2)) * 2048 + ko + sc,           \
            sb + w * 1024);

#define FP8_CORE_DECLS_AND_LOOP()                                              \
  const int lane = threadIdx.x & 63;                                           \
  const int w = threadIdx.x >> 6;                                              \
  const int q = lane >> 4, l16 = lane & 15;                                    \
  const int wm = (w >> 1) * 64, wn = (w & 1) * 64;                             \
  const int sc = (((lane & 3) ^ ((lane >> 3) & 3)) << 4);                      \
  f32x4 acc[4][4];                                                             \
  _Pragma("unroll") for (int i = 0; i < 4; ++i)                                \
      _Pragma("unroll") for (int j = 0; j < 4; ++j) acc[i][j] =                \
          (f32x4){0.f, 0.f, 0.f, 0.f};                                         \
  const int Xl = (l16 >> 1) & 3;                                               \
  int koff[2];                                                                 \
  _Pragma("unroll") for (int kh = 0; kh < 2; ++kh) koff[kh] =                  \
      (((kh * 2 + (q >> 1)) ^ Xl) << 4) + (q & 1) * 8;                         \
  {                                                                            \
    uint8_t* sa = &LA[0];                                                      \
    uint8_t* sb = &LB[0];                                                      \
    const int ko = 0;                                                          \
    STG_ALL()                                                                  \
  }                                                                            \
  asm volatile("s_waitcnt vmcnt(0)" ::: "memory");                             \
  __builtin_amdgcn_s_barrier();                                                \
  long af[4], bfr[4];                                                          \
  for (int t = 0; t < 31; ++t) {                                               \
    const int c = t & 1;                                                       \
    const uint8_t* la = &LA[c * 16384];                                        \
    const uint8_t* lb = &LB[c * 8192];                                         \
    uint8_t* sa = &LA[(c ^ 1) * 16384];                                        \
    uint8_t* sb = &LB[(c ^ 1) * 8192];                                         \
    const int ko = (t + 1) * 64;                                               \
    RD_AB(0)                                                                   \
    STG_ALL()                                                                  \
    __builtin_amdgcn_s_barrier();                                              \
    MFMA_4x4()                                                                 \
    __builtin_amdgcn_s_barrier();                                              \
    RD_AB(1)                                                                   \
    __builtin_amdgcn_s_barrier();                                              \
    MFMA_4x4()                                                                 \
    asm volatile("s_waitcnt vmcnt(0)" ::: "memory");                           \
    __builtin_amdgcn_s_barrier();                                              \
  }                                                                            \
  {                                                                            \
    const uint8_t* la = &LA[16384];                                            \
    const uint8_t* lb = &LB[8192];                                             \
    RD_AB(0)                                                                   \
    MFMA_4x4()                                                                 \
    RD_AB(1)                                                                   \
    MFMA_4x4()                                                                 \
  }

// --------------------- fp8 Gram GEMM: G = S·S^T ----------------------------
// 1D grid, batch = id % nb (XCD-pinned with nb=8: each XCD runs one batch,
// its 4MB S input L2-resident). tile idx = id / nb; lower-triangle 256x128
// tiles: ti in 0..7, tj in 0..2ti+1 (72/batch). Diagonal superblocks
// (tj>>1 == ti) computed fully; off-diagonal mirrored.
__global__ __launch_bounds__(512, 4) void gram_fp8_v2_k(
    const uint8_t* __restrict__ S, uint8_t* __restrict__ G,
    long long sS, long long sG, int nb) {
  __shared__ __align__(16) uint8_t LA[32768];
  __shared__ __align__(16) uint8_t LB[16384];
  const int b = blockIdx.x % nb;
  int idx = blockIdx.x / nb;
  const uint8_t* Sb = S + (long long)b * sS;
  uint8_t* Gb = G + (long long)b * sG;
  int ti = 0;
  while ((ti + 1) * (ti + 2) <= idx) ti++;
  const int tj = idx - ti * (ti + 1);
  const int m0 = ti * 256;
  const int n0 = tj * 128;
  const int T = 2048;
  const uint8_t* Ag = Sb + (long long)m0 * 2048;
  const uint8_t* Bg = Sb + (long long)n0 * 2048;

  FP8_CORE_DECLS_AND_LOOP()

  const bool mirror = ((tj >> 1) != ti);
#pragma unroll
  for (int i = 0; i < 4; ++i) {
#pragma unroll
    for (int j = 0; j < 4; ++j) {
      uint8_t bv[4];
#pragma unroll
      for (int r = 0; r < 4; ++r) {
        int row = m0 + wm + i * 16 + q * 4 + r;
        int col = n0 + wn + j * 16 + l16;
        uint8_t h = f2fp8(acc[i][j][r]);
        bv[r] = h;
        Gb[(long long)row * T + col] = h;
      }
      if (mirror) {
        int mrow = n0 + wn + j * 16 + l16;
        int mcol = m0 + wm + i * 16 + q * 4;
        uchar4 pk = {bv[0], bv[1], bv[2], bv[3]};
        *(uchar4*)(&Gb[(long long)mrow * T + mcol]) = pk;
      }
    }
  }
}

// ------------------- fp8 succ GEMM: succ = relu(G@STs^T - S*wd) ------------
// 1D grid, batch = id % nb (XCD-pinned); rem = id/nb in [0,128):
// m0 = (rem>>4)*256 (8 m-tiles), n0 = (rem&15)*128 (16 n-tiles) -> on one
// XCD consecutive blocks sweep n with fixed m: 512KB G-panel reused 16x,
// STs (4MB) cycles through L2.
__global__ __launch_bounds__(512, 4) void succ_fp8_v2_k(
    const uint8_t* __restrict__ G, const uint8_t* __restrict__ STs,
    uint16_t* __restrict__ C, const float* __restrict__ wd,
    long long sG, long long sB, long long sC, int nb) {
  __shared__ __align__(16) uint8_t LA[32768];
  __shared__ __align__(16) uint8_t LB[16384];
  const int b = blockIdx.x % nb;
  const int rem = blockIdx.x / nb;
  const uint8_t* Ab = G + (long long)b * sG;
  const uint8_t* Bb = STs + (long long)b * sB;
  uint16_t* Cb = C + (long long)b * sC;
  const float* wdb = wd + (long long)b * 2048;
  const int m0 = (rem >> 4) * 256;
  const int n0 = (rem & 15) * 128;
  const int N = 2048;
  const uint8_t* Ag = Ab + (long long)m0 * 2048;
  const uint8_t* Bg = Bb + (long long)n0 * 2048;

  FP8_CORE_DECLS_AND_LOOP()

  // epilogue: v = acc - S*wd ; S <- relu(v) (bf16, in place)
#pragma unroll
  for (int i = 0; i < 4; ++i) {
#pragma unroll
    for (int j = 0; j < 4; ++j) {
#pragma unroll
      for (int r = 0; r < 4; ++r) {
        int row = m0 + wm + i * 16 + q * 4 + r;
        int col = n0 + wn + j * 16 + l16;
        long long o = (long long)row * N + col;
        float sv = bf2f(Cb[o]);
        float v = acc[i][j][r] - sv * wdb[col];
        Cb[o] = f2bf(v > 0.f ? v : 0.f);
      }
    }
  }
}

// ------- transpose+shift+wdiag: S (TxN bf16) -> STs (NxT fp8), wd ----------
__global__ __launch_bounds__(256) void transpose_shift_wd_k(
    const uint16_t* __restrict__ S, uint8_t* __restrict__ STs,
    float* __restrict__ wd, int T, int N) {
  __shared__ uint16_t tile[65][72];
  __shared__ float wdl[64];
  int t0 = blockIdx.x * 64, n0 = blockIdx.y * 64, b = blockIdx.z;
  const uint16_t* Sb = S + (long long)b * T * N;
  for (int s = threadIdx.x; s < 65 * 8; s += 256) {
    int t = s >> 3, n8 = s & 7;
    u16x8 v = (u16x8){0, 0, 0, 0, 0, 0, 0, 0};
    if (t0 + t < T) v = *(const u16x8*)(Sb + (long long)(t0 + t) * N + n0 + n8 * 8);
    *(u16x8*)(&tile[t][n8 * 8]) = v;
  }
  if (threadIdx.x < 64) wdl[threadIdx.x] = 0.f;
  __syncthreads();
  uint8_t* STsb = STs + (long long)b * N * T;
  for (int s = threadIdx.x; s < 64 * 8; s += 256) {
    int n = s >> 3, t8 = s & 7;
    u8x8 c;
    float part = 0.f;
#pragma unroll
    for (int j = 0; j < 8; ++j) {
      float a = bf2f(tile[t8 * 8 + j][n]);
      float nb = bf2f(tile[t8 * 8 + j + 1][n]);
      c[j] = f2fp8(nb);
      part = fmaf(a, nb, part);
    }
    *(u8x8*)(STsb + (long long)(n0 + n) * T + t0 + t8 * 8) = c;
    atomicAdd(&wdl[n], part);
  }
  __syncthreads();
  if (threadIdx.x < 64)
    atomicAdd(&wd[(long long)b * N + n0 + threadIdx.x], wdl[threadIdx.x]);
}

// ---------------- shared selection core (ballot binary search) -------------
struct SelInfo {
  unsigned th;
  int cg[4];    // count > th per chunk
  int tc[4];    // count == th per chunk
  int r;        // tie slots to take (64 - total greater)
  float inv;    // 1/l2norm of the selected set
};

__device__ __forceinline__ SelInfo select64(const int k_[4][8],
                                            const u16x8 v[4]) {
  unsigned lo = 0, hi = 0x7FFF;
  while (lo < hi) {
    unsigned mid = (lo + hi) >> 1;
    int cnt = 0;
#pragma unroll
    for (int c = 0; c < 4; ++c)
#pragma unroll
      for (int i = 0; i < 8; ++i)
        cnt += (int)__popcll(__ballot(k_[c][i] > (int)mid));
    if (cnt < 64) hi = mid; else lo = mid + 1;
  }
  SelInfo s;
  s.th = lo;
  const int th = (int)lo;
  int cgt = 0;
#pragma unroll
  for (int c = 0; c < 4; ++c) {
    int cg = 0, tc = 0;
#pragma unroll
    for (int i = 0; i < 8; ++i) {
      cg += (int)__popcll(__ballot(k_[c][i] > th));
      tc += (int)__popcll(__ballot(k_[c][i] == th));
    }
    s.cg[c] = cg;
    s.tc[c] = tc;
    cgt += cg;
  }
  s.r = 64 - cgt;
  float ssq = 0.f;
#pragma unroll
  for (int c = 0; c < 4; ++c)
#pragma unroll
    for (int i = 0; i < 8; ++i)
      if (k_[c][i] > th) {
        float f = bf2f((unsigned)v[c][i]);
        ssq = fmaf(f, f, ssq);
      }
#pragma unroll
  for (int off = 32; off >= 1; off >>= 1) ssq += __shfl_xor(ssq, off, 64);
  float thf = bf2f(lo);
  float sumsq = ssq + (float)s.r * thf * thf;
  s.inv = 1.f / fmaxf(sqrtf(sumsq), 1e-10f);
  return s;
}

// ---------- topk1: one wave per row, dense bf16 + fp8 outputs --------------
__global__ __launch_bounds__(256) void topk1_k(
    const uint16_t* __restrict__ H, uint16_t* __restrict__ Sbf,
    uint8_t* __restrict__ Sf8) {
  const int lane = threadIdx.x & 63;
  const int wave = threadIdx.x >> 6;
  const long long row = (long long)blockIdx.x * 4 + wave;
  const uint16_t* h = H + row * 2048;

  u16x8 v[4];
  int k_[4][8];
#pragma unroll
  for (int c = 0; c < 4; ++c) {
    v[c] = *(const u16x8*)(h + c * 512 + lane * 8);
#pragma unroll
    for (int i = 0; i < 8; ++i) k_[c][i] = (int)v[c][i];
  }
  SelInfo s = select64(k_, v);
  const int th = (int)s.th;

  int tiebase = 0;
#pragma unroll
  for (int c = 0; c < 4; ++c) {
    int B = 0;
#pragma unroll
    for (int j = 0; j < 8; ++j)
      B += bits_below(__ballot(k_[c][j] == th));
    u16x8 o16;
    u8x8 o8;
    int own = 0;
#pragma unroll
    for (int i = 0; i < 8; ++i) {
      int kv = k_[c][i];
      bool ist = (kv == th);
      bool sel = (kv > th) || (ist && (tiebase + B + own) < s.r);
      if (ist) own++;
      float nv = sel ? bf2f((unsigned)v[c][i]) * s.inv : 0.f;
      o16[i] = sel ? (unsigned short)f2bf(nv) : (unsigned short)0;
      o8[i] = sel ? f2fp8(nv) : (uint8_t)0;
    }
    *(u16x8*)(Sbf + row * 2048 + c * 512 + lane * 8) = o16;
    *(u8x8*)(Sf8 + row * 2048 + c * 512 + lane * 8) = o8;
    tiebase += s.tc[c];
  }
}

// -------- topk2 + final: one wave per row, per-wave LDS slots, gather ------
__global__ __launch_bounds__(256) void topk2_final_k(
    const uint16_t* __restrict__ H, const float* __restrict__ x,
    const float* __restrict__ g, const uint16_t* __restrict__ upTb,
    float* __restrict__ out) {
  const int lane = threadIdx.x & 63;
  const int wave = threadIdx.x >> 6;
  const long long row = (long long)blockIdx.x * 4 + wave;
  const uint16_t* h = H + row * 2048;

  __shared__ int sidx[4][64];
  __shared__ float sval[4][64];

  u16x8 v[4];
  int k_[4][8];
#pragma unroll
  for (int c = 0; c < 4; ++c) {
    v[c] = *(const u16x8*)(h + c * 512 + lane * 8);
#pragma unroll
    for (int i = 0; i < 8; ++i) k_[c][i] = (int)v[c][i];
  }
  SelInfo s = select64(k_, v);
  const int th = (int)s.th;

  int tiebase = 0;
  int cum = 0;
#pragma unroll
  for (int c = 0; c < 4; ++c) {
    int B = 0;
#pragma unroll
    for (int j = 0; j < 8; ++j)
      B += bits_below(__ballot(k_[c][j] == th));
    int own = 0;
#pragma unroll
    for (int i = 0; i < 8; ++i) {
      int kv = k_[c][i];
      bool ist = (kv == th);
      bool sel = (kv > th) || (ist && (tiebase + B + own) < s.r);
      if (ist) own++;
      unsigned long long sm = __ballot(sel);
      if (sel) {
        int slot = cum + bits_below(sm);
        sidx[wave][slot] = c * 512 + lane * 8 + i;
        sval[wave][slot] = bf2f((unsigned)v[c][i]) * s.inv;
      }
      cum += (int)__popcll(sm);
    }
    tiebase += s.tc[c];
  }
  __syncthreads();

  const int col0 = lane * 8;
  float a[8] = {0.f, 0.f, 0.f, 0.f, 0.f, 0.f, 0.f, 0.f};
#pragma unroll 4
  for (int j = 0; j < 64; ++j) {
    int idx = sidx[wave][j];
    float w = sval[wave][j];
    const u16x8 pk = *(const u16x8*)(upTb + (long long)idx * 512 + col0);
#pragma unroll
    for (int q = 0; q < 8; ++q) a[q] = fmaf(w, bf2f((unsigned)pk[q]), a[q]);
  }
  long long o = row * 512 + col0;
  const float4 xv0 = *(const float4*)(x + o);
  const float4 xv1 = *(const float4*)(x + o + 4);
  const float4 gv0 = *(const float4*)(g + o);
  const float4 gv1 = *(const float4*)(g + o + 4);
  float4 r0, r1;
  r0.x = xv0.x + gv0.x * a[0];
  r0.y = xv0.y + gv0.y * a[1];
  r0.z = xv0.z + gv0.z * a[2];
  r0.w = xv0.w + gv0.w * a[3];
  r1.x = xv1.x + gv1.x * a[4];
  r1.y = xv1.y + gv1.y * a[5];
  r1.z = xv1.z + gv1.z * a[6];
  r1.w = xv1.w + gv1.w * a[7];
  *(float4*)(out + o) = r0;
  *(float4*)(out + o + 4) = r1;
}

// ---------------------------------------------------------------------------
extern "C" void kernel_launch(void* const* d_in, const int* in_sizes, int n_in,
                              void* d_out, int out_size, void* d_ws, size_t ws_size,
                              hipStream_t stream) {
  const float* x = (const float*)d_in[0];
  const float* downW = (const float*)d_in[1];
  const float* upW = (const float*)d_in[2];
  const float* gateW = (const float*)d_in[3];
  const float* gateB = (const float*)d_in[4];
  float* out = (float*)d_out;

  const int B = 8, T = 2048, D = 512, N = 2048;
  const long long BT = (long long)B * T;
  const long long TN = (long long)T * N;
  const long long TD = (long long)T * D;

  char* base = (char*)d_ws;
  size_t off = 0;
  auto take = [&](size_t bytes) {
    size_t o = off;
    off += (bytes + 255) & ~(size_t)255;
    return o;
  };
  size_t o_xb = take((size_t)BT * D * 2);
  size_t o_dwb = take((size_t)N * D * 2);
  size_t o_gwb = take((size_t)D * D * 2);
  size_t o_upT = take((size_t)N * D * 2);
  const size_t fixed = off;
  const size_t perb = (size_t)TN * 2 + (size_t)TN * 2 + (size_t)TN +
                      (size_t)TN + (size_t)N * 4;
  int Bc = 1;
  if (ws_size >= fixed + 8 * perb) Bc = 8;
  else if (ws_size >= fixed + 4 * perb) Bc = 4;
  else if (ws_size >= fixed + 2 * perb) Bc = 2;

  uint16_t* xb = (uint16_t*)(base + o_xb);
  uint16_t* dwb = (uint16_t*)(base + o_dwb);
  uint16_t* gwb = (uint16_t*)(base + o_gwb);
  uint16_t* upTb = (uint16_t*)(base + o_upT);
  char* p = base + fixed;
  uint16_t* R1 = (uint16_t*)p; p += (size_t)TN * 2 * Bc;  // h (bf16) -> G (fp8)
  uint16_t* R2 = (uint16_t*)p; p += (size_t)TN * 2 * Bc;  // S (bf16) -> succ
  uint8_t* R3 = (uint8_t*)p;  p += (size_t)TN * Bc;       // STs fp8 -> g fp32
  uint8_t* R4 = (uint8_t*)p;  p += (size_t)TN * Bc;       // S fp8
  float* wd = (float*)p;

  cast_f32_bf16_k<<<2048, 256, 0, stream>>>(x, xb, BT * D);
  cast_f32_bf16_k<<<512, 256, 0, stream>>>(downW, dwb, (long long)N * D);
  cast_f32_bf16_k<<<128, 256, 0, stream>>>(gateW, gwb, (long long)D * D);
  transpose_upw_k<<<dim3(N / 32, D / 32), 256, 0, stream>>>(upW, upTb, D, N);

  for (int b0 = 0; b0 < B; b0 += Bc) {
    const uint16_t* xc = xb + (long long)b0 * TD;
    gemm_bt_k<EPI_RELU_BF16><<<dim3(Bc * 16, 16, 1), 256, 0, stream>>>(
        xc, dwb, R1, nullptr, Bc * T, N, D);
    topk1_k<<<Bc * T / 4, 256, 0, stream>>>(R1, R2, R4);
    zero_f32_k<<<(Bc * N + 255) / 256, 256, 0, stream>>>(wd, (long long)Bc * N);
    transpose_shift_wd_k<<<dim3(T / 64, N / 64, Bc), 256, 0, stream>>>(
        R2, R3, wd, T, N);
    gram_fp8_v2_k<<<dim3(72 * Bc), 512, 0, stream>>>(
        R4, (uint8_t*)R1, TN, (long long)T * T, Bc);
    succ_fp8_v2_k<<<dim3(128 * Bc), 512, 0, stream>>>(
        (const uint8_t*)R1, R3, R2, wd, (long long)T * T, TN, TN, Bc);
    gemm_bt_k<EPI_SIG><<<dim3(Bc * 16, D / 128, 1), 256, 0, stream>>>(
        xc, gwb, (float*)R3, gateB, Bc * T, D, D);
    topk2_final_k<<<Bc * T / 4, 256, 0, stream>>>(
        R2, x + (long long)b0 * TD, (const float*)R3, upTb,
        out + (long long)b0 * TD);
  }
}